// Round 6
// baseline (81675.134 us; speedup 1.0000x reference)
//
#include <hip/hip_runtime.h>
#include <math.h>

// Problem constants
#define B 128
#define T 1024
#define E 256
#define H 512

// Persistent-kernel partition: 4 replicas x 64 blocks.
// replica r = bid & 3   -> owns batch rows [32r, 32r+32)
// unit blk bu = bid >> 2 -> owns units [8bu, 8bu+8)  (32 gate rows)
// 256 threads/block; per step two 16-row passes; thread = (gp, b):
//   gp = tid>>4 in [0,16): gate rows {2gp, 2gp+1}; b = tid&15.

// ws layout (floats):
//   hbuf  : [2][B][H]   (ping-pong h exchange)
//   last_h: [B][H]
//   last_c: [B][H]
//   Lsteps: 128 int
//   ctr   : 4 int (replica barrier counters)
#define HBUF_OFF   0
#define LASTH_OFF  (2*65536)
#define LASTC_OFF  (3*65536)
#define LSTEP_OFF  (4*65536)
#define CTR_OFF    (4*65536 + 128)

__device__ __forceinline__ float sigm_f(float x) {
    return 1.f / (1.f + expf(-x));
}
__device__ __forceinline__ void fma4(float4& a, const float4 w, const float4 x) {
    a.x = fmaf(w.x, x.x, a.x);
    a.y = fmaf(w.y, x.y, a.y);
    a.z = fmaf(w.z, x.z, a.z);
    a.w = fmaf(w.w, x.w, a.w);
}

// ---------------------------------------------------------------------------
// init: lengths, h0 -> hbuf[0] ([B][H] row-major), zero barrier counters
// grid 128 x 256
__global__ __launch_bounds__(256) void init_kernel(
    const int* __restrict__ tokens, const float* __restrict__ h0,
    float* __restrict__ ws) {
    const int b = blockIdx.x, tid = threadIdx.x;
    float* hbuf = ws + HBUF_OFF;
    int* Lsteps = (int*)(ws + LSTEP_OFF);
    int* ctr    = (int*)(ws + CTR_OFF);

    // copy h0 row b (512 floats = 128 float4)
    if (tid < 128)
        ((float4*)(hbuf + b * H))[tid] = ((const float4*)(h0 + b * H))[tid];
    if (b == 0 && tid < 4) ctr[tid] = 0;

    __shared__ int s_fz;
    if (tid == 0) s_fz = T;
    __syncthreads();
    int fz = T;
    for (int tt = tid; tt < T; tt += 256)
        if (tokens[b * T + tt] == 0) fz = min(fz, tt);
    atomicMin(&s_fz, fz);
    __syncthreads();
    if (tid == 0) {
        int f = s_fz;
        // steps to run = first_zero (>=1), or T if no zero / wrap (fz==0)
        Lsteps[b] = (f == 0 || f == T) ? T : f;
    }
}

// ---------------------------------------------------------------------------
// persistent LSTM: whole T-loop in one launch; replica-local barriers.
// grid 256 x 256
__global__ __launch_bounds__(256, 1) void lstm_persist(
    const int* __restrict__ tokens, const float* __restrict__ emb,
    const float* __restrict__ W_ih, const float* __restrict__ b_ih,
    const float* __restrict__ W_hh, const float* __restrict__ b_hh,
    const float* __restrict__ c0,
    float* __restrict__ hbuf, float* __restrict__ last_h,
    float* __restrict__ last_c, const int* __restrict__ Lsteps,
    int* __restrict__ ctr) {
    const int tid = threadIdx.x, bid = blockIdx.x;
    const int r  = bid & 3;          // replica
    const int bu = bid >> 2;         // unit block
    const int row0 = r * 32;

    __shared__ float xh[16 * 772];   // [row][k] k-pad 768->772 (stride%32==4)
    __shared__ float S[32 * 16];     // [gate-row][b]
    __shared__ int s_T;

    // replica step count (uniform across the replica's 64 blocks)
    if (tid == 0) {
        int m = 0;
        for (int i = 0; i < 32; ++i) m = max(m, Lsteps[row0 + i]);
        s_T = m;
    }

    // elementwise thread state (tid<128): unit = 8bu + (tid>>4), two rows
    const int ul_e = tid >> 4, b_e = tid & 15;
    const int unit_e = bu * 8 + ul_e;
    float creg[2];
    int   Lrow[2];
    float bsum[4];
    if (tid < 128) {
#pragma unroll
        for (int p = 0; p < 2; ++p) {
            const int row = row0 + p * 16 + b_e;
            creg[p] = c0[row * H + unit_e];
            Lrow[p] = Lsteps[row];
        }
#pragma unroll
        for (int g = 0; g < 4; ++g)
            bsum[g] = b_ih[g * H + unit_e] + b_hh[g * H + unit_e];
    }
    __syncthreads();
    const int Tg = s_T;

    // W row pointers: gate rows 2gp,2gp+1 = gate g = gp>>2, units uu,uu+1
    const int gp = tid >> 4, bb = tid & 15;
    const int gg = gp >> 2, uu = bu * 8 + ((2 * gp) & 7);
    const float4* wi0 = (const float4*)W_ih + (size_t)(gg * H + uu) * 64;
    const float4* wi1 = wi0 + 64;
    const float4* wh0 = (const float4*)W_hh + (size_t)(gg * H + uu) * 128;
    const float4* wh1 = wh0 + 128;

    for (int t = 0; t < Tg; ++t) {
        const float* hprev = hbuf + (t & 1) * (B * H);
        float*       hnext = hbuf + ((t + 1) & 1) * (B * H);

#pragma unroll 1
        for (int p = 0; p < 2; ++p) {
            const int prow = row0 + p * 16;
            // stage h: 16 rows x 128 f4
            {
                const float4* hp4 = (const float4*)(hprev + prow * H);
#pragma unroll
                for (int j = 0; j < 8; ++j) {
                    const int idx = tid + j * 256;
                    const int rl = idx >> 7, c4 = idx & 127;
                    *(float4*)&xh[rl * 772 + 256 + 4 * c4] = hp4[rl * 128 + c4];
                }
            }
            // stage x = emb[token]: 16 rows x 64 f4
            {
#pragma unroll
                for (int j = 0; j < 4; ++j) {
                    const int idx = tid + j * 256;
                    const int rl = idx >> 6, c4 = idx & 63;
                    const int tok = tokens[(prow + rl) * T + t];
                    *(float4*)&xh[rl * 772 + 4 * c4] =
                        ((const float4*)emb)[(size_t)tok * 64 + c4];
                }
            }
            __syncthreads();

            // 2 gate-rows x 1 batch-row dot products (768-K)
            float4 a0 = {0, 0, 0, 0}, a1 = {0, 0, 0, 0};
            const float4* xb = (const float4*)&xh[bb * 772];
#pragma unroll 8
            for (int k = 0; k < 64; ++k) {
                const float4 x = xb[k];
                fma4(a0, wi0[k], x);
                fma4(a1, wi1[k], x);
            }
#pragma unroll 8
            for (int k = 0; k < 128; ++k) {
                const float4 x = xb[64 + k];
                fma4(a0, wh0[k], x);
                fma4(a1, wh1[k], x);
            }
            S[(2 * gp) * 16 + bb]     = a0.x + a0.y + a0.z + a0.w;
            S[(2 * gp + 1) * 16 + bb] = a1.x + a1.y + a1.z + a1.w;
            __syncthreads();

            // elementwise for this 16-row half
            if (tid < 128) {
                const float ai = S[(0 * 8 + ul_e) * 16 + b_e] + bsum[0];
                const float af = S[(1 * 8 + ul_e) * 16 + b_e] + bsum[1];
                const float ag = S[(2 * 8 + ul_e) * 16 + b_e] + bsum[2];
                const float ao = S[(3 * 8 + ul_e) * 16 + b_e] + bsum[3];
                const float ig = sigm_f(ai);
                const float fg = sigm_f(af);
                const float gv = tanhf(ag);
                const float og = sigm_f(ao);
                const float cn = fg * creg[p] + ig * gv;
                const float hn = og * tanhf(cn);
                creg[p] = cn;
                const int row = prow + b_e;
                hnext[row * H + unit_e] = hn;
                if (t == Lrow[p] - 1) {
                    last_h[row * H + unit_e] = hn;
                    last_c[row * H + unit_e] = cn;
                }
            }
            // no extra sync: next pass's stage-sync (or step barrier) covers
            // S/xh reuse because every thread passes through it post-use.
            __syncthreads();
        }

        // replica barrier: all 64 blocks of replica r finished step t
        __threadfence();              // device-scope release (cross-XCD wb)
        __syncthreads();
        if (tid == 0) {
            __hip_atomic_fetch_add(&ctr[r], 1, __ATOMIC_RELEASE,
                                   __HIP_MEMORY_SCOPE_AGENT);
            const int target = 64 * (t + 1);
            while (__hip_atomic_load(&ctr[r], __ATOMIC_RELAXED,
                                     __HIP_MEMORY_SCOPE_AGENT) < target) {}
        }
        __syncthreads();
        __threadfence();              // device-scope acquire (L1/L2 inv)
    }
}

// ---------------------------------------------------------------------------
// final: y = [h;c] @ W_proj^T + b_proj ; out = y @ W_out^T + b_out
// grid 128 x 256; last_h/last_c are [B][H]
__global__ __launch_bounds__(256) void final_kernel(
    const float* __restrict__ last_h, const float* __restrict__ last_c,
    const float* __restrict__ W_proj, const float* __restrict__ b_proj,
    const float* __restrict__ W_out, const float* __restrict__ b_out,
    float* __restrict__ out) {
    const int bg = blockIdx.x, tid = threadIdx.x;

    __shared__ float s_hc[2 * H];
    __shared__ float s_y[H];
    for (int u = tid; u < H; u += 256) {
        s_hc[u]     = last_h[bg * H + u];
        s_hc[H + u] = last_c[bg * H + u];
    }
    __syncthreads();

    const float4* hc4 = (const float4*)s_hc;
    const float4* Wp4 = (const float4*)W_proj;
#pragma unroll
    for (int jj = 0; jj < 2; ++jj) {
        const int j = tid + jj * 256;
        const float4* wr = Wp4 + (size_t)j * 256;
        float4 acc = {0, 0, 0, 0};
#pragma unroll 4
        for (int kq = 0; kq < 256; ++kq) fma4(acc, wr[kq], hc4[kq]);
        s_y[j] = acc.x + acc.y + acc.z + acc.w + b_proj[j];
    }
    __syncthreads();

    if (tid < 64) {
        float p0 = 0.f, p1 = 0.f;
        for (int j = tid; j < H; j += 64) {
            const float y = s_y[j];
            p0 = fmaf(y, W_out[j], p0);
            p1 = fmaf(y, W_out[H + j], p1);
        }
#pragma unroll
        for (int off = 32; off; off >>= 1) {
            p0 += __shfl_down(p0, off);
            p1 += __shfl_down(p1, off);
        }
        if (tid == 0) {
            out[bg * 2 + 0] = p0 + b_out[0];
            out[bg * 2 + 1] = p1 + b_out[1];
        }
    }
}

// ---------------------------------------------------------------------------
extern "C" void kernel_launch(void* const* d_in, const int* in_sizes, int n_in,
                              void* d_out, int out_size, void* d_ws, size_t ws_size,
                              hipStream_t stream) {
    const int*   tokens = (const int*)d_in[0];
    const float* emb    = (const float*)d_in[1];
    const float* W_ih   = (const float*)d_in[2];
    const float* b_ih   = (const float*)d_in[3];
    const float* W_hh   = (const float*)d_in[4];
    const float* b_hh   = (const float*)d_in[5];
    const float* W_proj = (const float*)d_in[6];
    const float* b_proj = (const float*)d_in[7];
    const float* W_out  = (const float*)d_in[8];
    const float* b_out  = (const float*)d_in[9];
    const float* h0     = (const float*)d_in[10];
    const float* c0     = (const float*)d_in[11];
    float* out = (float*)d_out;
    float* ws  = (float*)d_ws;

    float* hbuf   = ws + HBUF_OFF;
    float* last_h = ws + LASTH_OFF;
    float* last_c = ws + LASTC_OFF;
    int*   Lsteps = (int*)(ws + LSTEP_OFF);
    int*   ctr    = (int*)(ws + CTR_OFF);

    hipLaunchKernelGGL(init_kernel, dim3(B), dim3(256), 0, stream,
                       tokens, h0, ws);

    hipLaunchKernelGGL(lstm_persist, dim3(256), dim3(256), 0, stream,
                       tokens, emb, W_ih, b_ih, W_hh, b_hh, c0,
                       hbuf, last_h, last_c, Lsteps, ctr);

    hipLaunchKernelGGL(final_kernel, dim3(B), dim3(256), 0, stream,
                       last_h, last_c, W_proj, b_proj, W_out, b_out, out);
}

// Round 7
// 30253.323 us; speedup vs baseline: 2.6997x; 2.6997x over previous
//
#include <hip/hip_runtime.h>
#include <math.h>

// Problem constants
#define B 128
#define T 1024
#define E 256
#define H 512

// Partition: 4 replicas x 64 blocks. replica r = bid & 3 owns batch rows
// [32r, 32r+32). Block bu = bid >> 2 owns units [8bu, 8bu+8) (32 gate rows).
// Thread: grp = tid>>5 (unit lane 0..7), kc = tid&31 (24-float K-chunk / row lane).
// W for (4 gates of unit) x (K-chunk) lives in 24 float4 REGISTERS for the whole
// kernel -> per-step fence/L2-invalidation cannot touch it (R6 post-mortem).

// ws layout (floats):
//   hbuf  : [2][H][B]  ping-pong h exchange (transposed: coalesced stores)
//   last_h: [H][B]
//   last_c: [H][B]
//   Lsteps: 128 int
//   ctr   : 4 replica counters, 32 ints apart (own cacheline each)
#define HBUF_OFF   0
#define LASTH_OFF  (2*65536)
#define LASTC_OFF  (3*65536)
#define LSTEP_OFF  (4*65536)
#define CTR_OFF    (4*65536 + 128)

// xh tile: 16 rows x 32 chunks x 28 floats (24 data + 4 pad; odd-f4 stride
// -> uniform LDS bank spread for the kc-parallel reads)
#define ROWSTRIDE 896            // floats per row
#define ROWSTRIDE4 224           // float4 per row

__device__ __forceinline__ float sigm_f(float x) {
    return 1.f / (1.f + expf(-x));
}
__device__ __forceinline__ void fma4(float4& a, const float4 w, const float4 x) {
    a.x = fmaf(w.x, x.x, a.x);
    a.y = fmaf(w.y, x.y, a.y);
    a.z = fmaf(w.z, x.z, a.z);
    a.w = fmaf(w.w, x.w, a.w);
}

// ---------------------------------------------------------------------------
// init: lengths, h0 -> hbuf[0] ([unit][B]), zero barrier counters
// grid 128 x 256
__global__ __launch_bounds__(256) void init_kernel(
    const int* __restrict__ tokens, const float* __restrict__ h0,
    float* __restrict__ ws) {
    const int b = blockIdx.x, tid = threadIdx.x;
    float* hbuf = ws + HBUF_OFF;
    int* Lsteps = (int*)(ws + LSTEP_OFF);
    int* ctr    = (int*)(ws + CTR_OFF);

    for (int u = tid; u < H; u += 256)
        hbuf[u * B + b] = h0[b * H + u];
    if (b == 0 && tid < 128) ctr[tid] = 0;

    __shared__ int s_fz;
    if (tid == 0) s_fz = T;
    __syncthreads();
    int fz = T;
    for (int tt = tid; tt < T; tt += 256)
        if (tokens[b * T + tt] == 0) fz = min(fz, tt);
    atomicMin(&s_fz, fz);
    __syncthreads();
    if (tid == 0) {
        int f = s_fz;
        // steps = first_zero (>=1), or T if no zero / wrap (first_zero==0)
        Lsteps[b] = (f == 0 || f == T) ? T : f;
    }
}

// ---------------------------------------------------------------------------
// persistent LSTM, W-in-registers, replica-local backoff barrier
// grid 256 x 256
__global__ __launch_bounds__(256, 1) void lstm_persist(
    const int* __restrict__ tokens, const float* __restrict__ emb,
    const float* __restrict__ W_ih, const float* __restrict__ b_ih,
    const float* __restrict__ W_hh, const float* __restrict__ b_hh,
    const float* __restrict__ c0,
    float* __restrict__ hbuf, float* __restrict__ last_h,
    float* __restrict__ last_c, const int* __restrict__ Lsteps,
    int* __restrict__ ctr) {
    const int tid = threadIdx.x, bid = blockIdx.x;
    const int r  = bid & 3;
    const int bu = bid >> 2;
    const int row0 = r * 32;
    const int grp = tid >> 5;          // unit lane 0..7
    const int kc  = tid & 31;          // K-chunk / batch-row lane
    const int unit = bu * 8 + grp;

    __shared__ float xh[16 * ROWSTRIDE];   // 57.3 KB
    __shared__ int s_T;

    if (tid == 0) {
        int m = 0;
        for (int i = 0; i < 32; ++i) m = max(m, Lsteps[row0 + i]);
        s_T = m;
    }

    // --- W into registers: 4 gates x 6 float4, cols [24kc, 24kc+24) of 768
    float4 wreg[4][6];
    {
        const int col0 = kc * 24;
#pragma unroll
        for (int g = 0; g < 4; ++g) {
            const int grow = g * H + unit;
#pragma unroll
            for (int j = 0; j < 6; ++j) {
                float v[4];
#pragma unroll
                for (int e = 0; e < 4; ++e) {
                    const int col = col0 + j * 4 + e;
                    v[e] = (col < E) ? W_ih[(size_t)grow * E + col]
                                     : W_hh[(size_t)grow * H + (col - E)];
                }
                wreg[g][j] = make_float4(v[0], v[1], v[2], v[3]);
            }
        }
    }
    float bsum[4];
#pragma unroll
    for (int g = 0; g < 4; ++g)
        bsum[g] = b_ih[g * H + unit] + b_hh[g * H + unit];

    const int myrow = row0 + kc;
    float creg = c0[(size_t)myrow * H + unit];
    const int Lrow = Lsteps[myrow];

    __syncthreads();
    const int Tg = s_T;

    for (int t = 0; t < Tg; ++t) {
        const float* hprev = hbuf + (t & 1) * (H * B);
        float*       hnext = hbuf + ((t + 1) & 1) * (H * B);

        float sel0 = 0.f, sel1 = 0.f, sel2 = 0.f, sel3 = 0.f;

        // ---- load half-0 globals (rows row0..row0+15) ----
        float4 pe[4], ph[8];
        {
            const int prow = row0;
#pragma unroll
            for (int i = 0; i < 4; ++i) {
                const int idx = tid + i * 256;
                const int rl = idx >> 6, c4 = idx & 63;
                const int tok = tokens[(size_t)(prow + rl) * T + t];
                pe[i] = ((const float4*)emb)[(size_t)tok * 64 + c4];
            }
            const float4* hp4 = (const float4*)hprev;
            const int qb = (prow >> 2);
#pragma unroll
            for (int i = 0; i < 8; ++i) {
                const int idx = tid + i * 256;
                const int u = idx >> 2, q = idx & 3;
                ph[i] = hp4[(size_t)u * 32 + qb + q];
            }
        }
        // ---- write half-0 to LDS ----
#pragma unroll
        for (int i = 0; i < 4; ++i) {
            const int idx = tid + i * 256;
            const int rl = idx >> 6, c4 = idx & 63;
            ((float4*)xh)[rl * ROWSTRIDE4 + (c4 / 6) * 7 + (c4 % 6)] = pe[i];
        }
#pragma unroll
        for (int i = 0; i < 8; ++i) {
            const int idx = tid + i * 256;
            const int u = idx >> 2, q = idx & 3;
            const int k = 256 + u, c = k / 24, rem = k % 24;
            float* d = &xh[(4 * q) * ROWSTRIDE + c * 28 + rem];
            d[0] = ph[i].x; d[ROWSTRIDE] = ph[i].y;
            d[2 * ROWSTRIDE] = ph[i].z; d[3 * ROWSTRIDE] = ph[i].w;
        }
        __syncthreads();

        // ---- prefetch half-1 globals (overlaps half-0 compute) ----
        {
            const int prow = row0 + 16;
#pragma unroll
            for (int i = 0; i < 4; ++i) {
                const int idx = tid + i * 256;
                const int rl = idx >> 6, c4 = idx & 63;
                const int tok = tokens[(size_t)(prow + rl) * T + t];
                pe[i] = ((const float4*)emb)[(size_t)tok * 64 + c4];
            }
            const float4* hp4 = (const float4*)hprev;
            const int qb = (prow >> 2);
#pragma unroll
            for (int i = 0; i < 8; ++i) {
                const int idx = tid + i * 256;
                const int u = idx >> 2, q = idx & 3;
                ph[i] = hp4[(size_t)u * 32 + qb + q];
            }
        }

        // ---- compute half-0: rows 0..15 ----
#pragma unroll 2
        for (int rr = 0; rr < 16; ++rr) {
            const float4* xb = ((const float4*)xh) + rr * ROWSTRIDE4 + kc * 7;
            float4 a0 = {0,0,0,0}, a1 = {0,0,0,0}, a2 = {0,0,0,0}, a3 = {0,0,0,0};
#pragma unroll
            for (int j = 0; j < 6; ++j) {
                const float4 x = xb[j];
                fma4(a0, wreg[0][j], x);
                fma4(a1, wreg[1][j], x);
                fma4(a2, wreg[2][j], x);
                fma4(a3, wreg[3][j], x);
            }
            float s0 = a0.x + a0.y + a0.z + a0.w;
            float s1 = a1.x + a1.y + a1.z + a1.w;
            float s2 = a2.x + a2.y + a2.z + a2.w;
            float s3 = a3.x + a3.y + a3.z + a3.w;
#pragma unroll
            for (int m = 1; m <= 16; m <<= 1) {
                s0 += __shfl_xor(s0, m);
                s1 += __shfl_xor(s1, m);
                s2 += __shfl_xor(s2, m);
                s3 += __shfl_xor(s3, m);
            }
            if (kc == rr) { sel0 = s0; sel1 = s1; sel2 = s2; sel3 = s3; }
        }
        __syncthreads();

        // ---- write half-1 to LDS ----
#pragma unroll
        for (int i = 0; i < 4; ++i) {
            const int idx = tid + i * 256;
            const int rl = idx >> 6, c4 = idx & 63;
            ((float4*)xh)[rl * ROWSTRIDE4 + (c4 / 6) * 7 + (c4 % 6)] = pe[i];
        }
#pragma unroll
        for (int i = 0; i < 8; ++i) {
            const int idx = tid + i * 256;
            const int u = idx >> 2, q = idx & 3;
            const int k = 256 + u, c = k / 24, rem = k % 24;
            float* d = &xh[(4 * q) * ROWSTRIDE + c * 28 + rem];
            d[0] = ph[i].x; d[ROWSTRIDE] = ph[i].y;
            d[2 * ROWSTRIDE] = ph[i].z; d[3 * ROWSTRIDE] = ph[i].w;
        }
        __syncthreads();

        // ---- compute half-1: rows 16..31 ----
#pragma unroll 2
        for (int rr = 0; rr < 16; ++rr) {
            const float4* xb = ((const float4*)xh) + rr * ROWSTRIDE4 + kc * 7;
            float4 a0 = {0,0,0,0}, a1 = {0,0,0,0}, a2 = {0,0,0,0}, a3 = {0,0,0,0};
#pragma unroll
            for (int j = 0; j < 6; ++j) {
                const float4 x = xb[j];
                fma4(a0, wreg[0][j], x);
                fma4(a1, wreg[1][j], x);
                fma4(a2, wreg[2][j], x);
                fma4(a3, wreg[3][j], x);
            }
            float s0 = a0.x + a0.y + a0.z + a0.w;
            float s1 = a1.x + a1.y + a1.z + a1.w;
            float s2 = a2.x + a2.y + a2.z + a2.w;
            float s3 = a3.x + a3.y + a3.z + a3.w;
#pragma unroll
            for (int m = 1; m <= 16; m <<= 1) {
                s0 += __shfl_xor(s0, m);
                s1 += __shfl_xor(s1, m);
                s2 += __shfl_xor(s2, m);
                s3 += __shfl_xor(s3, m);
            }
            if (kc == 16 + rr) { sel0 = s0; sel1 = s1; sel2 = s2; sel3 = s3; }
        }

        // ---- elementwise (each thread owns (unit, myrow)) ----
        {
            const float ig = sigm_f(sel0 + bsum[0]);
            const float fg = sigm_f(sel1 + bsum[1]);
            const float gv = tanhf(sel2 + bsum[2]);
            const float og = sigm_f(sel3 + bsum[3]);
            const float cn = fg * creg + ig * gv;
            const float hn = og * tanhf(cn);
            creg = cn;
            hnext[(size_t)unit * B + myrow] = hn;
            if (t == Lrow - 1) {
                last_h[(size_t)unit * B + myrow] = hn;
                last_c[(size_t)unit * B + myrow] = cn;
            }
        }

        // ---- replica barrier: release-add, backoff poll, acquire ----
        __syncthreads();   // drains each wave's vmcnt (h stores in L2)
        if (tid == 0) {
            __hip_atomic_fetch_add(&ctr[r * 32], 1, __ATOMIC_RELEASE,
                                   __HIP_MEMORY_SCOPE_AGENT);
            const int target = 64 * (t + 1);
            while (__hip_atomic_load(&ctr[r * 32], __ATOMIC_RELAXED,
                                     __HIP_MEMORY_SCOPE_AGENT) < target)
                __builtin_amdgcn_s_sleep(2);
        }
        __syncthreads();
        __builtin_amdgcn_fence(__ATOMIC_ACQUIRE, "agent");
    }
}

// ---------------------------------------------------------------------------
// final: y = [h;c] @ W_proj^T + b_proj ; out = y @ W_out^T + b_out
// grid 128 x 256; last buffers are [unit][B]
__global__ __launch_bounds__(256) void final_kernel(
    const float* __restrict__ last_h, const float* __restrict__ last_c,
    const float* __restrict__ W_proj, const float* __restrict__ b_proj,
    const float* __restrict__ W_out, const float* __restrict__ b_out,
    float* __restrict__ out) {
    const int bg = blockIdx.x, tid = threadIdx.x;

    __shared__ float s_hc[2 * H];
    __shared__ float s_y[H];
    for (int u = tid; u < H; u += 256) {
        s_hc[u]     = last_h[u * B + bg];
        s_hc[H + u] = last_c[u * B + bg];
    }
    __syncthreads();

    const float4* hc4 = (const float4*)s_hc;
    const float4* Wp4 = (const float4*)W_proj;
#pragma unroll
    for (int jj = 0; jj < 2; ++jj) {
        const int j = tid + jj * 256;
        const float4* wr = Wp4 + (size_t)j * 256;
        float4 acc = {0, 0, 0, 0};
#pragma unroll 4
        for (int kq = 0; kq < 256; ++kq) fma4(acc, wr[kq], hc4[kq]);
        s_y[j] = acc.x + acc.y + acc.z + acc.w + b_proj[j];
    }
    __syncthreads();

    if (tid < 64) {
        float p0 = 0.f, p1 = 0.f;
        for (int j = tid; j < H; j += 64) {
            const float y = s_y[j];
            p0 = fmaf(y, W_out[j], p0);
            p1 = fmaf(y, W_out[H + j], p1);
        }
#pragma unroll
        for (int off = 32; off; off >>= 1) {
            p0 += __shfl_down(p0, off);
            p1 += __shfl_down(p1, off);
        }
        if (tid == 0) {
            out[bg * 2 + 0] = p0 + b_out[0];
            out[bg * 2 + 1] = p1 + b_out[1];
        }
    }
}

// ---------------------------------------------------------------------------
extern "C" void kernel_launch(void* const* d_in, const int* in_sizes, int n_in,
                              void* d_out, int out_size, void* d_ws, size_t ws_size,
                              hipStream_t stream) {
    const int*   tokens = (const int*)d_in[0];
    const float* emb    = (const float*)d_in[1];
    const float* W_ih   = (const float*)d_in[2];
    const float* b_ih   = (const float*)d_in[3];
    const float* W_hh   = (const float*)d_in[4];
    const float* b_hh   = (const float*)d_in[5];
    const float* W_proj = (const float*)d_in[6];
    const float* b_proj = (const float*)d_in[7];
    const float* W_out  = (const float*)d_in[8];
    const float* b_out  = (const float*)d_in[9];
    const float* h0     = (const float*)d_in[10];
    const float* c0     = (const float*)d_in[11];
    float* out = (float*)d_out;
    float* ws  = (float*)d_ws;

    float* hbuf   = ws + HBUF_OFF;
    float* last_h = ws + LASTH_OFF;
    float* last_c = ws + LASTC_OFF;
    int*   Lsteps = (int*)(ws + LSTEP_OFF);
    int*   ctr    = (int*)(ws + CTR_OFF);

    hipLaunchKernelGGL(init_kernel, dim3(B), dim3(256), 0, stream,
                       tokens, h0, ws);

    hipLaunchKernelGGL(lstm_persist, dim3(256), dim3(256), 0, stream,
                       tokens, emb, W_ih, b_ih, W_hh, b_hh, c0,
                       hbuf, last_h, last_c, Lsteps, ctr);

    hipLaunchKernelGGL(final_kernel, dim3(B), dim3(256), 0, stream,
                       last_h, last_c, W_proj, b_proj, W_out, b_out, out);
}